// Round 1
// baseline (1082.268 us; speedup 1.0000x reference)
//
#include <hip/hip_runtime.h>
#include <math.h>

#define NN 2048
#define MM 32
#define DD 768
#define HH 512
constexpr float TEMP = 0.05f;
constexpr float THRESH = 1e-4f;
constexpr float EPS = 1e-6f;

// ---------------------------------------------------------------------------
// build_A: Arow[i][h] = sum_d X[i][d]*W1a[d][h] + |X[i][d]-q[d]|*W1d[d][h]
// Tile: 16 rows x 128 cols, BK=16. Grid (128, 4) = 512 blocks.
// ---------------------------------------------------------------------------
__global__ __launch_bounds__(256) void build_A_kernel(
    const float* __restrict__ X, const float* __restrict__ q,
    const float* __restrict__ W1, float* __restrict__ Arow)
{
    __shared__ float Zs[16][16];    // [kk][row]
    __shared__ float Ws[16][128];
    __shared__ float qs[DD];
    const int t = threadIdx.x;
    const int lane = t & 63;
    const int ty = t >> 6;          // wave 0..3
    const int i0 = blockIdx.x * 16;
    const int h0 = blockIdx.y * 128;
    for (int idx = t; idx < DD; idx += 256) qs[idx] = q[idx];

    float acc[4][2] = {};
    for (int term = 0; term < 2; ++term) {
        const float* W = W1 + (term ? (size_t)2304 * HH : 0) + h0;
        for (int d0 = 0; d0 < DD; d0 += 16) {
            __syncthreads();
            {   // X tile 16x16 (transposed into Zs)
                int r = t >> 4, c = t & 15;
                float v = X[(size_t)(i0 + r) * DD + d0 + c];
                if (term) v = fabsf(v - qs[d0 + c]);
                Zs[c][r] = v;
            }
            #pragma unroll
            for (int rep = 0; rep < 2; ++rep) {   // W tile 16x128
                int idx = rep * 256 + t;
                int row = idx >> 5;
                int c4 = (idx & 31) * 4;
                *(float4*)(&Ws[row][c4]) =
                    *(const float4*)(W + (size_t)(d0 + row) * HH + c4);
            }
            __syncthreads();
            #pragma unroll
            for (int kk = 0; kk < 16; ++kk) {
                float z[4], w[2];
                #pragma unroll
                for (int r = 0; r < 4; ++r) z[r] = Zs[kk][4 * ty + r];
                w[0] = Ws[kk][lane];
                w[1] = Ws[kk][lane + 64];
                #pragma unroll
                for (int r = 0; r < 4; ++r) {
                    acc[r][0] = fmaf(z[r], w[0], acc[r][0]);
                    acc[r][1] = fmaf(z[r], w[1], acc[r][1]);
                }
            }
        }
    }
    #pragma unroll
    for (int r = 0; r < 4; ++r) {
        int i = i0 + 4 * ty + r;
        Arow[(size_t)i * HH + h0 + lane]      = acc[r][0];
        Arow[(size_t)i * HH + h0 + lane + 64] = acc[r][1];
    }
}

// ---------------------------------------------------------------------------
// build_B: Brow[j][h] = b1[h] + sum_d y[d]*W1b[d][h] + |y[d]-q[d]|*W1e[d][h]
// ---------------------------------------------------------------------------
__global__ __launch_bounds__(256) void build_B_kernel(
    const float* __restrict__ C_init, const float* __restrict__ q,
    const float* __restrict__ W1, const float* __restrict__ b1,
    float* __restrict__ Brow)
{
    __shared__ float ys[DD], ya[DD];
    const int j = blockIdx.x, t = threadIdx.x;
    for (int idx = t; idx < DD; idx += 256) {
        float y = C_init[(size_t)j * DD + idx];
        ys[idx] = y;
        ya[idx] = fabsf(y - q[idx]);
    }
    __syncthreads();
    const float* W1b = W1 + (size_t)768 * HH;
    const float* W1e = W1 + (size_t)3072 * HH;
    #pragma unroll
    for (int hh = 0; hh < 2; ++hh) {
        int h = t + hh * 256;
        float acc = b1[h];
        for (int d = 0; d < DD; ++d) {
            acc = fmaf(ys[d], W1b[(size_t)d * HH + h], acc);
            acc = fmaf(ya[d], W1e[(size_t)d * HH + h], acc);
        }
        Brow[(size_t)j * HH + h] = acc;
    }
}

// ---------------------------------------------------------------------------
// pairwise: the big one. For each (i-tile of 32, j):
//   P[i,h] = sum_d |X[i][d]-Y[j][d]| * W1c[d][h]      (K=768 loop, BK=16)
//   s[i,j] = sum_h relu(P + Arow[i,h] + Brow[j,h]) * W2[h]   (fused epilogue)
// Grid (64, 32) = 2048 blocks, 256 threads, 64 fp32 acc/thread.
// ---------------------------------------------------------------------------
__global__ __launch_bounds__(256) void pairwise_kernel(
    const float* __restrict__ X, const float* __restrict__ W1,
    const float* __restrict__ Y,
    const float* __restrict__ Arow, const float* __restrict__ Brow,
    const float* __restrict__ W2, float* __restrict__ S)
{
    __shared__ float Zs[16][32];     // [kk][row]
    __shared__ float Ws[16][HH];     // 32 KB
    __shared__ float ys[DD];
    const int t = threadIdx.x;
    const int lane = t & 63;
    const int ty = t >> 6;           // wave 0..3 -> rows 8*ty..8*ty+7
    const int i0 = blockIdx.x * 32;
    const int j  = blockIdx.y;

    for (int idx = t; idx < DD; idx += 256) ys[idx] = Y[(size_t)j * DD + idx];

    const float* W1c = W1 + (size_t)1536 * HH;
    float acc[8][8];
    #pragma unroll
    for (int r = 0; r < 8; ++r)
        #pragma unroll
        for (int c = 0; c < 8; ++c) acc[r][c] = 0.f;

    for (int d0 = 0; d0 < DD; d0 += 16) {
        __syncthreads();
        if (t < 128) {   // X tile 32x16 -> |x-y| transposed into Zs
            int r = t >> 2;
            int c4 = (t & 3) * 4;
            const float4 xv = *(const float4*)(X + (size_t)(i0 + r) * DD + d0 + c4);
            Zs[c4 + 0][r] = fabsf(xv.x - ys[d0 + c4 + 0]);
            Zs[c4 + 1][r] = fabsf(xv.y - ys[d0 + c4 + 1]);
            Zs[c4 + 2][r] = fabsf(xv.z - ys[d0 + c4 + 2]);
            Zs[c4 + 3][r] = fabsf(xv.w - ys[d0 + c4 + 3]);
        }
        #pragma unroll
        for (int rep = 0; rep < 8; ++rep) {   // W1c tile 16x512
            int idx = rep * 256 + t;
            int row = idx >> 7;
            int c4 = (idx & 127) * 4;
            *(float4*)(&Ws[row][c4]) =
                *(const float4*)(W1c + (size_t)(d0 + row) * HH + c4);
        }
        __syncthreads();
        #pragma unroll
        for (int kk = 0; kk < 16; ++kk) {
            float z[8], w[8];
            #pragma unroll
            for (int r = 0; r < 8; ++r) z[r] = Zs[kk][8 * ty + r];   // b128 broadcast
            #pragma unroll
            for (int c = 0; c < 8; ++c) w[c] = Ws[kk][lane + 64 * c]; // conflict-free
            #pragma unroll
            for (int r = 0; r < 8; ++r)
                #pragma unroll
                for (int c = 0; c < 8; ++c)
                    acc[r][c] = fmaf(z[r], w[c], acc[r][c]);
        }
    }

    // fused epilogue: relu(P + A + B) . W2, then wave-reduce over h (64 lanes)
    #pragma unroll
    for (int r = 0; r < 8; ++r) {
        const int i = i0 + 8 * ty + r;
        float p = 0.f;
        #pragma unroll
        for (int c = 0; c < 8; ++c) {
            const int h = lane + 64 * c;
            float pre = acc[r][c] + Arow[(size_t)i * HH + h] + Brow[(size_t)j * HH + h];
            p = fmaf(fmaxf(pre, 0.f), W2[h], p);
        }
        #pragma unroll
        for (int off = 32; off >= 1; off >>= 1) p += __shfl_xor(p, off, 64);
        if (lane == 0) S[(size_t)i * MM + j] = p;
    }
}

// ---------------------------------------------------------------------------
// softmax over j (M=32) of -sigmoid(s+b2)/TEMP; writes a. 8 rows/block.
// ---------------------------------------------------------------------------
__global__ __launch_bounds__(256) void softmax_kernel(
    const float* __restrict__ S, const float* __restrict__ b2,
    float* __restrict__ a_out)
{
    const int t = threadIdx.x;
    const int j = t & 31, r = t >> 5;
    const int i = blockIdx.x * 8 + r;
    const float b2v = b2[0];
    float s = S[(size_t)i * MM + j];
    float sig = 1.f / (1.f + expf(-(s + b2v)));
    float l = -sig * (1.0f / TEMP);
    float m = l;
    #pragma unroll
    for (int off = 16; off >= 1; off >>= 1) m = fmaxf(m, __shfl_xor(m, off, 32));
    float e = expf(l - m);
    float sum = e;
    #pragma unroll
    for (int off = 16; off >= 1; off >>= 1) sum += __shfl_xor(sum, off, 32);
    a_out[(size_t)i * MM + j] = e / sum;
}

// ---------------------------------------------------------------------------
// C_new[j][d] = (sum_i a[i][j]*X[i][d]) / (sum_i a[i][j] + EPS)
// also accumulates diff = sum |C_new - C_init| (atomic per wave).
// Grid (3, 32), 256 threads, d = bx*256 + t.
// ---------------------------------------------------------------------------
__global__ __launch_bounds__(256) void cnew_kernel(
    const float* __restrict__ a, const float* __restrict__ X,
    const float* __restrict__ C_init, float* __restrict__ C_new,
    float* __restrict__ diff)
{
    const int t = threadIdx.x;
    const int j = blockIdx.y;
    const int d = blockIdx.x * 256 + t;
    float acc = 0.f, asum = 0.f;
    for (int i = 0; i < NN; ++i) {
        float av = a[(size_t)i * MM + j];
        asum += av;
        acc = fmaf(av, X[(size_t)i * DD + d], acc);
    }
    float c = acc / (asum + EPS);
    C_new[(size_t)j * DD + d] = c;
    float ad = fabsf(c - C_init[(size_t)j * DD + d]);
    #pragma unroll
    for (int off = 32; off >= 1; off >>= 1) ad += __shfl_xor(ad, off, 64);
    if ((t & 63) == 0) atomicAdd(diff, ad);
}

__global__ __launch_bounds__(256) void select_kernel(
    const float* __restrict__ C_new, const float* __restrict__ C_init,
    const float* __restrict__ diff, float* __restrict__ out)
{
    const int k = blockIdx.x * 256 + threadIdx.x;
    const float dv = *diff;
    out[k] = (dv > THRESH) ? C_new[k] : C_init[k];
}

// ---------------------------------------------------------------------------
extern "C" void kernel_launch(void* const* d_in, const int* in_sizes, int n_in,
                              void* d_out, int out_size, void* d_ws, size_t ws_size,
                              hipStream_t stream)
{
    const float* q      = (const float*)d_in[0];
    const float* X      = (const float*)d_in[1];
    const float* C_init = (const float*)d_in[2];
    const float* W1     = (const float*)d_in[3];
    const float* b1     = (const float*)d_in[4];
    const float* W2     = (const float*)d_in[5];
    const float* b2     = (const float*)d_in[6];

    float* out_C = (float*)d_out;                    // (M, D) = 24576
    float* out_a = (float*)d_out + (size_t)MM * DD;  // (N, M) = 65536

    float* ws   = (float*)d_ws;
    float* Arow = ws;                                // N*H = 1048576
    float* Brow = Arow + (size_t)NN * HH;            // M*H = 16384
    float* S    = Brow + (size_t)MM * HH;            // N*M = 65536
    float* Cn   = S    + (size_t)NN * MM;            // M*D = 24576
    float* diff = Cn   + (size_t)MM * DD;            // 1

    hipMemsetAsync(diff, 0, sizeof(float), stream);
    build_A_kernel<<<dim3(128, 4), 256, 0, stream>>>(X, q, W1, Arow);
    build_B_kernel<<<32, 256, 0, stream>>>(C_init, q, W1, b1, Brow);
    pairwise_kernel<<<dim3(64, 32), 256, 0, stream>>>(X, W1, C_init, Arow, Brow, W2, S);
    softmax_kernel<<<256, 256, 0, stream>>>(S, b2, out_a);
    cnew_kernel<<<dim3(3, 32), 256, 0, stream>>>(out_a, X, C_init, Cn, diff);
    select_kernel<<<96, 256, 0, stream>>>(Cn, C_init, diff, out_C);
}

// Round 2
// 913.420 us; speedup vs baseline: 1.1849x; 1.1849x over previous
//
#include <hip/hip_runtime.h>
#include <math.h>

#define NN 2048
#define MM 32
#define DD 768
#define HH 512
constexpr float TEMP = 0.05f;
constexpr float THRESH = 1e-4f;
constexpr float EPS = 1e-6f;

#define WLD 520   // Ws row stride (words): 512 + 8, keeps 16B alignment
#define ZLDP 68   // Zs row stride for 64-row tiles (bank shift 4)
#define ZLDA 36   // Zs row stride for 32-row tiles (bank shift 4)

// XOR-bit2 swizzle so stride-8-word column reads cover all 32 banks.
__device__ __forceinline__ int wswz(int c) { return c ^ (((c >> 5) & 1) << 2); }

// ---------------------------------------------------------------------------
// build_A: Arow[i][h] += partial GEMM over K-chunk.
// Tile 32 i x 512 h, grid (64 i-blocks, 4 splits = term x k-half), K=384 each.
// Thread tile 8x8. Merged into Arow via atomicAdd (Arow pre-zeroed).
// ---------------------------------------------------------------------------
__global__ __launch_bounds__(256, 2) void build_A_kernel(
    const float* __restrict__ X, const float* __restrict__ q,
    const float* __restrict__ W1, float* __restrict__ Arow)
{
    __shared__ float Ws[16 * WLD];
    __shared__ float Zs[16 * ZLDA];
    __shared__ float qs[384];
    const int t = threadIdx.x;
    const int lane = t & 63;
    const int ty = t >> 6;
    const int i0 = blockIdx.x * 32;
    const int s = blockIdx.y;            // 0..3
    const int term = s >> 1;
    const int kbase = (s & 1) * 384;
    const int wrow0 = (term ? 2304 : 0) + kbase;

    if (term) for (int idx = t; idx < 384; idx += 256) qs[idx] = q[kbase + idx];

    const int s4 = ((lane >> 2) & 1) << 2;
    const int p_lo = 8 * lane + s4;
    const int p_hi = 8 * lane + (4 ^ s4);

    float acc[8][8];
    #pragma unroll
    for (int r = 0; r < 8; ++r)
        #pragma unroll
        for (int c = 0; c < 8; ++c) acc[r][c] = 0.f;

    for (int d0 = 0; d0 < 384; d0 += 16) {
        __syncthreads();
        if (t < 128) {   // Z tile 32 rows x 16 kk
            int r = t >> 2;
            int c4 = (t & 3) * 4;
            float4 xv = *(const float4*)(X + (size_t)(i0 + r) * DD + kbase + d0 + c4);
            if (term) {
                xv.x = fabsf(xv.x - qs[d0 + c4 + 0]);
                xv.y = fabsf(xv.y - qs[d0 + c4 + 1]);
                xv.z = fabsf(xv.z - qs[d0 + c4 + 2]);
                xv.w = fabsf(xv.w - qs[d0 + c4 + 3]);
            }
            Zs[(c4 + 0) * ZLDA + r] = xv.x;
            Zs[(c4 + 1) * ZLDA + r] = xv.y;
            Zs[(c4 + 2) * ZLDA + r] = xv.z;
            Zs[(c4 + 3) * ZLDA + r] = xv.w;
        }
        #pragma unroll
        for (int rep = 0; rep < 8; ++rep) {   // W tile 16 x 512, swizzled
            int idx = rep * 256 + t;
            int row = idx >> 7;
            int c4 = (idx & 127) * 4;
            *(float4*)(&Ws[row * WLD + wswz(c4)]) =
                *(const float4*)(W1 + (size_t)(wrow0 + d0 + row) * HH + c4);
        }
        __syncthreads();
        #pragma unroll
        for (int kk = 0; kk < 16; ++kk) {
            float z[8], w[8];
            *(float4*)&z[0] = *(float4*)&Zs[kk * ZLDA + 8 * ty + 0];
            *(float4*)&z[4] = *(float4*)&Zs[kk * ZLDA + 8 * ty + 4];
            *(float4*)&w[0] = *(float4*)&Ws[kk * WLD + p_lo];
            *(float4*)&w[4] = *(float4*)&Ws[kk * WLD + p_hi];
            #pragma unroll
            for (int r = 0; r < 8; ++r)
                #pragma unroll
                for (int c = 0; c < 8; ++c)
                    acc[r][c] = fmaf(z[r], w[c], acc[r][c]);
        }
    }
    #pragma unroll
    for (int r = 0; r < 8; ++r) {
        const int i = i0 + 8 * ty + r;
        #pragma unroll
        for (int c = 0; c < 8; ++c)
            atomicAdd(&Arow[(size_t)i * HH + 8 * lane + c], acc[r][c]);
    }
}

// ---------------------------------------------------------------------------
// build_B: Brow[j][h] = b1[h] + y@W1b + |y-q|@W1e. Grid (32 j, 2 h-chunks).
// ---------------------------------------------------------------------------
__global__ __launch_bounds__(256) void build_B_kernel(
    const float* __restrict__ C_init, const float* __restrict__ q,
    const float* __restrict__ W1, const float* __restrict__ b1,
    float* __restrict__ Brow)
{
    __shared__ float ys[DD], ya[DD];
    const int j = blockIdx.x, t = threadIdx.x;
    const int h = blockIdx.y * 256 + t;
    for (int idx = t; idx < DD; idx += 256) {
        float y = C_init[(size_t)j * DD + idx];
        ys[idx] = y;
        ya[idx] = fabsf(y - q[idx]);
    }
    __syncthreads();
    const float* W1b = W1 + (size_t)768 * HH + h;
    const float* W1e = W1 + (size_t)3072 * HH + h;
    float acc = b1[h];
    #pragma unroll 8
    for (int d = 0; d < DD; ++d)
        acc = fmaf(ys[d], W1b[(size_t)d * HH], fmaf(ya[d], W1e[(size_t)d * HH], acc));
    Brow[(size_t)j * HH + h] = acc;
}

// ---------------------------------------------------------------------------
// pairwise: per (64-i-tile, j): P = |X-y| @ W1c (K=768), fused epilogue
// s[i,j] = sum_h relu(P+A+B)*W2[h]. Thread tile 16x8, all-b128 LDS.
// Grid (32, 32) = 1024 blocks.
// ---------------------------------------------------------------------------
__global__ __launch_bounds__(256, 2) void pairwise_kernel(
    const float* __restrict__ X, const float* __restrict__ W1,
    const float* __restrict__ Y,
    const float* __restrict__ Arow, const float* __restrict__ Brow,
    const float* __restrict__ W2, float* __restrict__ S)
{
    __shared__ float Ws[16 * WLD];   // 33.3 KB
    __shared__ float Zs[16 * ZLDP];  // 4.3 KB
    __shared__ float ys[DD];         // 3 KB
    const int t = threadIdx.x;
    const int lane = t & 63;
    const int ty = t >> 6;           // wave -> rows 16*ty..16*ty+15
    const int i0 = blockIdx.x * 64;
    const int j  = blockIdx.y;

    for (int idx = t; idx < DD; idx += 256) ys[idx] = Y[(size_t)j * DD + idx];

    const float* W1c = W1 + (size_t)1536 * HH;
    const int s4 = ((lane >> 2) & 1) << 2;
    const int p_lo = 8 * lane + s4;        // physical word of logical col 8*lane
    const int p_hi = 8 * lane + (4 ^ s4);  // physical word of logical col 8*lane+4

    float acc[16][8];
    #pragma unroll
    for (int r = 0; r < 16; ++r)
        #pragma unroll
        for (int c = 0; c < 8; ++c) acc[r][c] = 0.f;

    for (int d0 = 0; d0 < DD; d0 += 16) {
        __syncthreads();
        {   // Z tile: 64 rows x 16 kk of |x - y|, layout [kk][row], LD=68
            int r = t >> 2;
            int c4 = (t & 3) * 4;
            float4 xv = *(const float4*)(X + (size_t)(i0 + r) * DD + d0 + c4);
            Zs[(c4 + 0) * ZLDP + r] = fabsf(xv.x - ys[d0 + c4 + 0]);
            Zs[(c4 + 1) * ZLDP + r] = fabsf(xv.y - ys[d0 + c4 + 1]);
            Zs[(c4 + 2) * ZLDP + r] = fabsf(xv.z - ys[d0 + c4 + 2]);
            Zs[(c4 + 3) * ZLDP + r] = fabsf(xv.w - ys[d0 + c4 + 3]);
        }
        #pragma unroll
        for (int rep = 0; rep < 8; ++rep) {   // W1c tile 16 x 512, swizzled
            int idx = rep * 256 + t;
            int row = idx >> 7;
            int c4 = (idx & 127) * 4;
            *(float4*)(&Ws[row * WLD + wswz(c4)]) =
                *(const float4*)(W1c + (size_t)(d0 + row) * HH + c4);
        }
        __syncthreads();
        #pragma unroll
        for (int kk = 0; kk < 16; ++kk) {
            float z[16], w[8];
            #pragma unroll
            for (int r4 = 0; r4 < 16; r4 += 4)
                *(float4*)&z[r4] = *(float4*)&Zs[kk * ZLDP + 16 * ty + r4];
            *(float4*)&w[0] = *(float4*)&Ws[kk * WLD + p_lo];
            *(float4*)&w[4] = *(float4*)&Ws[kk * WLD + p_hi];
            #pragma unroll
            for (int r = 0; r < 16; ++r)
                #pragma unroll
                for (int c = 0; c < 8; ++c)
                    acc[r][c] = fmaf(z[r], w[c], acc[r][c]);
        }
    }

    // epilogue: relu(P + A + B) . W2 over this thread's cols, reduce over wave
    float w2[8];
    *(float4*)&w2[0] = *(const float4*)(W2 + 8 * lane);
    *(float4*)&w2[4] = *(const float4*)(W2 + 8 * lane + 4);
    float bv[8];
    *(float4*)&bv[0] = *(const float4*)(Brow + (size_t)j * HH + 8 * lane);
    *(float4*)&bv[4] = *(const float4*)(Brow + (size_t)j * HH + 8 * lane + 4);

    #pragma unroll
    for (int r = 0; r < 16; ++r) {
        const int i = i0 + 16 * ty + r;
        float av[8];
        *(float4*)&av[0] = *(const float4*)(Arow + (size_t)i * HH + 8 * lane);
        *(float4*)&av[4] = *(const float4*)(Arow + (size_t)i * HH + 8 * lane + 4);
        float p = 0.f;
        #pragma unroll
        for (int c = 0; c < 8; ++c) {
            float pre = acc[r][c] + av[c] + bv[c];
            p = fmaf(fmaxf(pre, 0.f), w2[c], p);
        }
        #pragma unroll
        for (int off = 32; off >= 1; off >>= 1) p += __shfl_xor(p, off, 64);
        if (lane == 0) S[(size_t)i * MM + j] = p;
    }
}

// ---------------------------------------------------------------------------
// softmax over j (M=32) of -sigmoid(s+b2)/TEMP. 8 rows/block.
// ---------------------------------------------------------------------------
__global__ __launch_bounds__(256) void softmax_kernel(
    const float* __restrict__ S, const float* __restrict__ b2,
    float* __restrict__ a_out)
{
    const int t = threadIdx.x;
    const int j = t & 31, r = t >> 5;
    const int i = blockIdx.x * 8 + r;
    const float b2v = b2[0];
    float s = S[(size_t)i * MM + j];
    float sig = 1.f / (1.f + expf(-(s + b2v)));
    float l = -sig * (1.0f / TEMP);
    float m = l;
    #pragma unroll
    for (int off = 16; off >= 1; off >>= 1) m = fmaxf(m, __shfl_xor(m, off, 32));
    float e = expf(l - m);
    float sum = e;
    #pragma unroll
    for (int off = 16; off >= 1; off >>= 1) sum += __shfl_xor(sum, off, 32);
    a_out[(size_t)i * MM + j] = e / sum;
}

// ---------------------------------------------------------------------------
// cnew stage 1: partial sums over 256-i chunks, atomically merged.
// Grid (3 d-chunks, 32 j, 8 i-chunks).
// ---------------------------------------------------------------------------
__global__ __launch_bounds__(256) void cnew_partial_kernel(
    const float* __restrict__ a, const float* __restrict__ X,
    float* __restrict__ Cacc, float* __restrict__ Asum)
{
    const int t = threadIdx.x;
    const int d = blockIdx.x * 256 + t;
    const int j = blockIdx.y;
    const int i0 = blockIdx.z * 256;
    float acc = 0.f, asum = 0.f;
    for (int ii = 0; ii < 256; ++ii) {
        float av = a[(size_t)(i0 + ii) * MM + j];
        asum += av;
        acc = fmaf(av, X[(size_t)(i0 + ii) * DD + d], acc);
    }
    atomicAdd(&Cacc[(size_t)j * DD + d], acc);
    if (blockIdx.x == 0 && t == 0) atomicAdd(&Asum[j], asum);
}

__global__ __launch_bounds__(256) void finalize_kernel(
    const float* __restrict__ Cacc, const float* __restrict__ Asum,
    const float* __restrict__ C_init, float* __restrict__ C_new,
    float* __restrict__ diff)
{
    const int t = threadIdx.x;
    const int d = blockIdx.x * 256 + t;
    const int j = blockIdx.y;
    float c = Cacc[(size_t)j * DD + d] / (Asum[j] + EPS);
    C_new[(size_t)j * DD + d] = c;
    float ad = fabsf(c - C_init[(size_t)j * DD + d]);
    #pragma unroll
    for (int off = 32; off >= 1; off >>= 1) ad += __shfl_xor(ad, off, 64);
    if ((t & 63) == 0) atomicAdd(diff, ad);
}

__global__ __launch_bounds__(256) void select_kernel(
    const float* __restrict__ C_new, const float* __restrict__ C_init,
    const float* __restrict__ diff, float* __restrict__ out)
{
    const int k = blockIdx.x * 256 + threadIdx.x;
    const float dv = *diff;
    out[k] = (dv > THRESH) ? C_new[k] : C_init[k];
}

// ---------------------------------------------------------------------------
extern "C" void kernel_launch(void* const* d_in, const int* in_sizes, int n_in,
                              void* d_out, int out_size, void* d_ws, size_t ws_size,
                              hipStream_t stream)
{
    const float* q      = (const float*)d_in[0];
    const float* X      = (const float*)d_in[1];
    const float* C_init = (const float*)d_in[2];
    const float* W1     = (const float*)d_in[3];
    const float* b1     = (const float*)d_in[4];
    const float* W2     = (const float*)d_in[5];
    const float* b2     = (const float*)d_in[6];

    float* out_C = (float*)d_out;                    // (M, D)
    float* out_a = (float*)d_out + (size_t)MM * DD;  // (N, M)

    float* ws   = (float*)d_ws;
    float* Arow = ws;                                // N*H
    float* Brow = Arow + (size_t)NN * HH;            // M*H
    float* S    = Brow + (size_t)MM * HH;            // N*M
    float* Cacc = S    + (size_t)NN * MM;            // M*D
    float* Asum = Cacc + (size_t)MM * DD;            // M
    float* diff = Asum + MM;                         // 1
    float* Cn   = diff + 1;                          // M*D

    hipMemsetAsync(Arow, 0, (size_t)NN * HH * sizeof(float), stream);
    hipMemsetAsync(Cacc, 0, ((size_t)MM * DD + MM + 1) * sizeof(float), stream);

    build_A_kernel<<<dim3(64, 4), 256, 0, stream>>>(X, q, W1, Arow);
    build_B_kernel<<<dim3(32, 2), 256, 0, stream>>>(C_init, q, W1, b1, Brow);
    pairwise_kernel<<<dim3(32, 32), 256, 0, stream>>>(X, W1, C_init, Arow, Brow, W2, S);
    softmax_kernel<<<256, 256, 0, stream>>>(S, b2, out_a);
    cnew_partial_kernel<<<dim3(3, 32, 8), 256, 0, stream>>>(out_a, X, Cacc, Asum);
    finalize_kernel<<<dim3(3, 32), 256, 0, stream>>>(Cacc, Asum, C_init, Cn, diff);
    select_kernel<<<96, 256, 0, stream>>>(Cn, C_init, diff, out_C);
}

// Round 3
// 433.588 us; speedup vs baseline: 2.4961x; 2.1067x over previous
//
#include <hip/hip_runtime.h>
#include <hip/hip_fp16.h>
#include <math.h>

#define NN 2048
#define MM 32
#define DD 768
#define HH 512
#define KT 24   // 768 / 32 k-tiles
constexpr float TEMP = 0.05f;
constexpr float THRESH = 1e-4f;
constexpr float EPS = 1e-6f;

#define WLD 520   // Ws row stride (words) for fp32 build_A
#define ZLDA 36   // Zs row stride for 32-row tiles (bank shift 4)

typedef _Float16 halfx8 __attribute__((ext_vector_type(8)));
typedef float floatx4 __attribute__((ext_vector_type(4)));

// XOR-bit2 swizzle (build_A fp32 path)
__device__ __forceinline__ int wswz(int c) { return c ^ (((c >> 5) & 1) << 2); }

// ---------------------------------------------------------------------------
// prep_W: W1c (fp32, [k][n] k=1536..2303) -> Wf fp16 frag-ordered:
// Wf[kt][nt][lane][j] = W1c[kt*32 + (lane>>4)*8 + j][nt*16 + (lane&15)]
// One block per kt (24 blocks). Stage tile in LDS, write coalesced-ish.
// ---------------------------------------------------------------------------
__global__ __launch_bounds__(256) void prep_W_kernel(
    const float* __restrict__ W1, _Float16* __restrict__ Wf)
{
    __shared__ float Wt[32 * 512];   // 64 KB
    const int kt = blockIdx.x;
    const int t = threadIdx.x;
    #pragma unroll
    for (int rep = 0; rep < 16; ++rep) {
        int idx = rep * 256 + t;
        int row = idx >> 7;
        int c4 = (idx & 127) * 4;
        *(float4*)&Wt[row * 512 + c4] =
            *(const float4*)(W1 + (size_t)(1536 + kt * 32 + row) * HH + c4);
    }
    __syncthreads();
    // each thread writes 64 consecutive fp16 (one 8-half vector at a time)
    #pragma unroll
    for (int g = 0; g < 8; ++g) {
        halfx8 v;
        #pragma unroll
        for (int jj = 0; jj < 8; ++jj) {
            int o = t * 64 + g * 8 + jj;        // o = nt*512 + l*8 + j
            int nt = o >> 9;
            int l  = (o >> 3) & 63;
            int j  = o & 7;
            int k  = ((l >> 4) << 3) + j;
            int n  = nt * 16 + (l & 15);
            v[jj] = (_Float16)Wt[k * 512 + n];
        }
        *(halfx8*)(Wf + (size_t)kt * 16384 + t * 64 + g * 8) = v;
    }
}

// ---------------------------------------------------------------------------
// build_A (fp32 VALU, unchanged from R2): Arow = X@W1a + |X-q|@W1d
// ---------------------------------------------------------------------------
__global__ __launch_bounds__(256, 2) void build_A_kernel(
    const float* __restrict__ X, const float* __restrict__ q,
    const float* __restrict__ W1, float* __restrict__ Arow)
{
    __shared__ float Ws[16 * WLD];
    __shared__ float Zs[16 * ZLDA];
    __shared__ float qs[384];
    const int t = threadIdx.x;
    const int lane = t & 63;
    const int ty = t >> 6;
    const int i0 = blockIdx.x * 32;
    const int s = blockIdx.y;
    const int term = s >> 1;
    const int kbase = (s & 1) * 384;
    const int wrow0 = (term ? 2304 : 0) + kbase;

    if (term) for (int idx = t; idx < 384; idx += 256) qs[idx] = q[kbase + idx];

    const int s4 = ((lane >> 2) & 1) << 2;
    const int p_lo = 8 * lane + s4;
    const int p_hi = 8 * lane + (4 ^ s4);

    float acc[8][8];
    #pragma unroll
    for (int r = 0; r < 8; ++r)
        #pragma unroll
        for (int c = 0; c < 8; ++c) acc[r][c] = 0.f;

    for (int d0 = 0; d0 < 384; d0 += 16) {
        __syncthreads();
        if (t < 128) {
            int r = t >> 2;
            int c4 = (t & 3) * 4;
            float4 xv = *(const float4*)(X + (size_t)(i0 + r) * DD + kbase + d0 + c4);
            if (term) {
                xv.x = fabsf(xv.x - qs[d0 + c4 + 0]);
                xv.y = fabsf(xv.y - qs[d0 + c4 + 1]);
                xv.z = fabsf(xv.z - qs[d0 + c4 + 2]);
                xv.w = fabsf(xv.w - qs[d0 + c4 + 3]);
            }
            Zs[(c4 + 0) * ZLDA + r] = xv.x;
            Zs[(c4 + 1) * ZLDA + r] = xv.y;
            Zs[(c4 + 2) * ZLDA + r] = xv.z;
            Zs[(c4 + 3) * ZLDA + r] = xv.w;
        }
        #pragma unroll
        for (int rep = 0; rep < 8; ++rep) {
            int idx = rep * 256 + t;
            int row = idx >> 7;
            int c4 = (idx & 127) * 4;
            *(float4*)(&Ws[row * WLD + wswz(c4)]) =
                *(const float4*)(W1 + (size_t)(wrow0 + d0 + row) * HH + c4);
        }
        __syncthreads();
        #pragma unroll
        for (int kk = 0; kk < 16; ++kk) {
            float z[8], w[8];
            *(float4*)&z[0] = *(float4*)&Zs[kk * ZLDA + 8 * ty + 0];
            *(float4*)&z[4] = *(float4*)&Zs[kk * ZLDA + 8 * ty + 4];
            *(float4*)&w[0] = *(float4*)&Ws[kk * WLD + p_lo];
            *(float4*)&w[4] = *(float4*)&Ws[kk * WLD + p_hi];
            #pragma unroll
            for (int r = 0; r < 8; ++r)
                #pragma unroll
                for (int c = 0; c < 8; ++c)
                    acc[r][c] = fmaf(z[r], w[c], acc[r][c]);
        }
    }
    #pragma unroll
    for (int r = 0; r < 8; ++r) {
        const int i = i0 + 8 * ty + r;
        #pragma unroll
        for (int c = 0; c < 8; ++c)
            atomicAdd(&Arow[(size_t)i * HH + 8 * lane + c], acc[r][c]);
    }
}

// ---------------------------------------------------------------------------
// build_B (unchanged): Brow[j][h] = b1[h] + y@W1b + |y-q|@W1e
// ---------------------------------------------------------------------------
__global__ __launch_bounds__(256) void build_B_kernel(
    const float* __restrict__ C_init, const float* __restrict__ q,
    const float* __restrict__ W1, const float* __restrict__ b1,
    float* __restrict__ Brow)
{
    __shared__ float ys[DD], ya[DD];
    const int j = blockIdx.x, t = threadIdx.x;
    const int h = blockIdx.y * 256 + t;
    for (int idx = t; idx < DD; idx += 256) {
        float y = C_init[(size_t)j * DD + idx];
        ys[idx] = y;
        ya[idx] = fabsf(y - q[idx]);
    }
    __syncthreads();
    const float* W1b = W1 + (size_t)768 * HH + h;
    const float* W1e = W1 + (size_t)3072 * HH + h;
    float acc = b1[h];
    #pragma unroll 8
    for (int d = 0; d < DD; ++d)
        acc = fmaf(ys[d], W1b[(size_t)d * HH], fmaf(ya[d], W1e[(size_t)d * HH], acc));
    Brow[(size_t)j * HH + h] = acc;
}

// ---------------------------------------------------------------------------
// pairwise_mfma: P = |X - y_j| @ W1c via 2-pass fp16-split MFMA, fused
// epilogue s[i,j] = sum_h relu(P + A + B) * W2[h].
// Block: 128 i x 512 h, 512 threads (8 waves, 4 row-groups x 2 col-halves).
// Wave: 32 rows x 256 cols = 2 rowtiles x 16 coltiles of 16x16 (128 AGPR).
// B-fragments come straight from frag-ordered global Wf (no LDS round-trip).
// Grid (16, 32).
// ---------------------------------------------------------------------------
__global__ __launch_bounds__(512, 2) void pairwise_mfma_kernel(
    const float* __restrict__ X, const _Float16* __restrict__ Wf,
    const float* __restrict__ Y,
    const float* __restrict__ Arow, const float* __restrict__ Brow,
    const float* __restrict__ W2, float* __restrict__ S)
{
    __shared__ _Float16 Zh[128 * 40];   // row stride 40 halves (80 B) - bank-safe
    __shared__ _Float16 Zl[128 * 40];
    __shared__ float ys[DD];
    __shared__ float Sred[2 * 128];
    const int t = threadIdx.x;
    const int lane = t & 63;
    const int wv = t >> 6;       // 0..7
    const int wr = wv >> 1;      // row group: rows 32*wr .. 32*wr+31
    const int wc = wv & 1;       // col half: cols 256*wc ..
    const int q4 = lane >> 4;    // quad
    const int l16 = lane & 15;
    const int i0 = blockIdx.x * 128;
    const int j  = blockIdx.y;

    for (int d = t; d < DD; d += 512) ys[d] = Y[(size_t)j * DD + d];

    floatx4 acc[2][16];
    #pragma unroll
    for (int rt = 0; rt < 2; ++rt)
        #pragma unroll
        for (int ct = 0; ct < 16; ++ct) acc[rt][ct] = (floatx4)0.f;

    const int zr = t >> 2;        // 0..127 (row for Z staging)
    const int zk = (t & 3) * 8;   // k-offset within 32

    for (int kt = 0; kt < KT; ++kt) {
        __syncthreads();
        {   // stage Z = |x - y| split into fp16 hi/lo
            const float* xp = X + (size_t)(i0 + zr) * DD + kt * 32 + zk;
            float4 xa = *(const float4*)xp;
            float4 xb = *(const float4*)(xp + 4);
            float z[8];
            z[0] = fabsf(xa.x - ys[kt * 32 + zk + 0]);
            z[1] = fabsf(xa.y - ys[kt * 32 + zk + 1]);
            z[2] = fabsf(xa.z - ys[kt * 32 + zk + 2]);
            z[3] = fabsf(xa.w - ys[kt * 32 + zk + 3]);
            z[4] = fabsf(xb.x - ys[kt * 32 + zk + 4]);
            z[5] = fabsf(xb.y - ys[kt * 32 + zk + 5]);
            z[6] = fabsf(xb.z - ys[kt * 32 + zk + 6]);
            z[7] = fabsf(xb.w - ys[kt * 32 + zk + 7]);
            halfx8 vh, vl;
            #pragma unroll
            for (int e = 0; e < 8; ++e) {
                _Float16 h = (_Float16)z[e];
                vh[e] = h;
                vl[e] = (_Float16)(z[e] - (float)h);
            }
            *(halfx8*)&Zh[zr * 40 + zk] = vh;
            *(halfx8*)&Zl[zr * 40 + zk] = vl;
        }
        __syncthreads();

        halfx8 Ah[2], Al[2];
        #pragma unroll
        for (int rt = 0; rt < 2; ++rt) {
            int r = wr * 32 + rt * 16 + l16;
            Ah[rt] = *(halfx8*)&Zh[r * 40 + q4 * 8];
            Al[rt] = *(halfx8*)&Zl[r * 40 + q4 * 8];
        }
        const _Float16* wp = Wf + (((size_t)kt * 32 + wc * 16) * 64 + lane) * 8;
        #pragma unroll
        for (int ct = 0; ct < 16; ++ct) {
            halfx8 B = *(const halfx8*)(wp + (size_t)ct * 512);
            #pragma unroll
            for (int rt = 0; rt < 2; ++rt) {
                acc[rt][ct] = __builtin_amdgcn_mfma_f32_16x16x32_f16(Ah[rt], B, acc[rt][ct], 0, 0, 0);
                acc[rt][ct] = __builtin_amdgcn_mfma_f32_16x16x32_f16(Al[rt], B, acc[rt][ct], 0, 0, 0);
            }
        }
    }

    // epilogue: lane holds rows i0+wr*32+rt*16+q4*4+reg, col h = wc*256+ct*16+l16
    float w2v[16], bv[16];
    #pragma unroll
    for (int ct = 0; ct < 16; ++ct) {
        int h = wc * 256 + ct * 16 + l16;
        w2v[ct] = W2[h];
        bv[ct]  = Brow[(size_t)j * HH + h];
    }
    #pragma unroll
    for (int rt = 0; rt < 2; ++rt) {
        #pragma unroll
        for (int reg = 0; reg < 4; ++reg) {
            int row = wr * 32 + rt * 16 + q4 * 4 + reg;
            const float* ap = Arow + (size_t)(i0 + row) * HH + wc * 256 + l16;
            float s = 0.f;
            #pragma unroll
            for (int ct = 0; ct < 16; ++ct) {
                float pre = acc[rt][ct][reg] + ap[ct * 16] + bv[ct];
                s = fmaf(fmaxf(pre, 0.f), w2v[ct], s);
            }
            s += __shfl_xor(s, 1, 64);
            s += __shfl_xor(s, 2, 64);
            s += __shfl_xor(s, 4, 64);
            s += __shfl_xor(s, 8, 64);
            if (l16 == 0) Sred[wc * 128 + row] = s;
        }
    }
    __syncthreads();
    if (t < 128) S[(size_t)(i0 + t) * MM + j] = Sred[t] + Sred[128 + t];
}

// ---------------------------------------------------------------------------
__global__ __launch_bounds__(256) void softmax_kernel(
    const float* __restrict__ S, const float* __restrict__ b2,
    float* __restrict__ a_out)
{
    const int t = threadIdx.x;
    const int j = t & 31, r = t >> 5;
    const int i = blockIdx.x * 8 + r;
    const float b2v = b2[0];
    float s = S[(size_t)i * MM + j];
    float sig = 1.f / (1.f + expf(-(s + b2v)));
    float l = -sig * (1.0f / TEMP);
    float m = l;
    #pragma unroll
    for (int off = 16; off >= 1; off >>= 1) m = fmaxf(m, __shfl_xor(m, off, 32));
    float e = expf(l - m);
    float sum = e;
    #pragma unroll
    for (int off = 16; off >= 1; off >>= 1) sum += __shfl_xor(sum, off, 32);
    a_out[(size_t)i * MM + j] = e / sum;
}

__global__ __launch_bounds__(256) void cnew_partial_kernel(
    const float* __restrict__ a, const float* __restrict__ X,
    float* __restrict__ Cacc, float* __restrict__ Asum)
{
    const int t = threadIdx.x;
    const int d = blockIdx.x * 256 + t;
    const int j = blockIdx.y;
    const int i0 = blockIdx.z * 256;
    float acc = 0.f, asum = 0.f;
    for (int ii = 0; ii < 256; ++ii) {
        float av = a[(size_t)(i0 + ii) * MM + j];
        asum += av;
        acc = fmaf(av, X[(size_t)(i0 + ii) * DD + d], acc);
    }
    atomicAdd(&Cacc[(size_t)j * DD + d], acc);
    if (blockIdx.x == 0 && t == 0) atomicAdd(&Asum[j], asum);
}

__global__ __launch_bounds__(256) void finalize_kernel(
    const float* __restrict__ Cacc, const float* __restrict__ Asum,
    const float* __restrict__ C_init, float* __restrict__ C_new,
    float* __restrict__ diff)
{
    const int t = threadIdx.x;
    const int d = blockIdx.x * 256 + t;
    const int j = blockIdx.y;
    float c = Cacc[(size_t)j * DD + d] / (Asum[j] + EPS);
    C_new[(size_t)j * DD + d] = c;
    float ad = fabsf(c - C_init[(size_t)j * DD + d]);
    #pragma unroll
    for (int off = 32; off >= 1; off >>= 1) ad += __shfl_xor(ad, off, 64);
    if ((t & 63) == 0) atomicAdd(diff, ad);
}

__global__ __launch_bounds__(256) void select_kernel(
    const float* __restrict__ C_new, const float* __restrict__ C_init,
    const float* __restrict__ diff, float* __restrict__ out)
{
    const int k = blockIdx.x * 256 + threadIdx.x;
    const float dv = *diff;
    out[k] = (dv > THRESH) ? C_new[k] : C_init[k];
}

// ---------------------------------------------------------------------------
extern "C" void kernel_launch(void* const* d_in, const int* in_sizes, int n_in,
                              void* d_out, int out_size, void* d_ws, size_t ws_size,
                              hipStream_t stream)
{
    const float* q      = (const float*)d_in[0];
    const float* X      = (const float*)d_in[1];
    const float* C_init = (const float*)d_in[2];
    const float* W1     = (const float*)d_in[3];
    const float* b1     = (const float*)d_in[4];
    const float* W2     = (const float*)d_in[5];
    const float* b2     = (const float*)d_in[6];

    float* out_C = (float*)d_out;                    // (M, D)
    float* out_a = (float*)d_out + (size_t)MM * DD;  // (N, M)

    // ws layout (16B-aligned chunks; Wf first for halfx8 alignment)
    float* ws   = (float*)d_ws;
    _Float16* Wf = (_Float16*)ws;                    // 24*16384 fp16 = 393216 halves
    float* Arow = ws + 196608;                       // N*H  (Wf = 196608 floats)
    float* Brow = Arow + (size_t)NN * HH;            // M*H
    float* S    = Brow + (size_t)MM * HH;            // N*M
    float* Cacc = S    + (size_t)NN * MM;            // M*D
    float* Asum = Cacc + (size_t)MM * DD;            // M
    float* diff = Asum + MM;                         // 1 (+15 pad)
    float* Cn   = diff + 16;                         // M*D

    hipMemsetAsync(Arow, 0, (size_t)NN * HH * sizeof(float), stream);
    hipMemsetAsync(Cacc, 0, ((size_t)MM * DD + MM + 16) * sizeof(float), stream);

    prep_W_kernel<<<KT, 256, 0, stream>>>(W1, Wf);
    build_A_kernel<<<dim3(64, 4), 256, 0, stream>>>(X, q, W1, Arow);
    build_B_kernel<<<dim3(32, 2), 256, 0, stream>>>(C_init, q, W1, b1, Brow);
    pairwise_mfma_kernel<<<dim3(16, 32), 512, 0, stream>>>(X, Wf, C_init, Arow, Brow, W2, S);
    softmax_kernel<<<256, 256, 0, stream>>>(S, b2, out_a);
    cnew_partial_kernel<<<dim3(3, 32, 8), 256, 0, stream>>>(out_a, X, Cacc, Asum);
    finalize_kernel<<<dim3(3, 32), 256, 0, stream>>>(Cacc, Asum, C_init, Cn, diff);
    select_kernel<<<96, 256, 0, stream>>>(Cn, C_init, diff, out_C);
}

// Round 4
// 307.889 us; speedup vs baseline: 3.5151x; 1.4083x over previous
//
#include <hip/hip_runtime.h>
#include <hip/hip_fp16.h>
#include <math.h>

#define NN 2048
#define MM 32
#define DD 768
#define HH 512
#define KT 24   // 768 / 32 k-tiles
constexpr float TEMP = 0.05f;
constexpr float THRESH = 1e-4f;
constexpr float EPS = 1e-6f;

typedef _Float16 halfx8 __attribute__((ext_vector_type(8)));
typedef float floatx4 __attribute__((ext_vector_type(4)));

// ---------------------------------------------------------------------------
// prep_W: convert 3 W1 blocks (a: rows 0.., c: 1536.., d: 2304..) to fp16
// frag-ordered Wf[wb][kt][nt][lane][j] = W1[rowbase + kt*32 + (lane>>4)*8 + j]
//                                          [nt*16 + (lane&15)]
// Grid 72 = 3 wb x 24 kt.
// ---------------------------------------------------------------------------
__global__ __launch_bounds__(256) void prep_W_kernel(
    const float* __restrict__ W1, _Float16* __restrict__ Wf)
{
    __shared__ float Wt[32 * 512];   // 64 KB
    const int wb = blockIdx.x / 24;
    const int kt = blockIdx.x % 24;
    const int rowbase = (wb == 0) ? 0 : (wb == 1 ? 1536 : 2304);
    const int t = threadIdx.x;
    #pragma unroll
    for (int rep = 0; rep < 16; ++rep) {
        int idx = rep * 256 + t;
        int row = idx >> 7;
        int c4 = (idx & 127) * 4;
        *(float4*)&Wt[row * 512 + c4] =
            *(const float4*)(W1 + (size_t)(rowbase + kt * 32 + row) * HH + c4);
    }
    __syncthreads();
    #pragma unroll
    for (int g = 0; g < 8; ++g) {
        halfx8 v;
        #pragma unroll
        for (int jj = 0; jj < 8; ++jj) {
            int o = t * 64 + g * 8 + jj;        // o = nt*512 + l*8 + j
            int nt = o >> 9;
            int l  = (o >> 3) & 63;
            int j  = o & 7;
            int k  = ((l >> 4) << 3) + j;
            int n  = nt * 16 + (l & 15);
            v[jj] = (_Float16)Wt[k * 512 + n];
        }
        *(halfx8*)(Wf + ((size_t)wb * KT + kt) * 16384 + t * 64 + g * 8) = v;
    }
}

// ---------------------------------------------------------------------------
// build_A_mfma: Arow = X@W1a + |X-q|@W1d via 2-pass fp16-split MFMA.
// Block: 32 i x 512 h, 512 threads = 8 waves (2 row-groups x 4 col-quarters).
// Wave: 16 rows x 128 cols = 8 coltiles of 16x16. Direct stores, no atomics.
// Grid 64.
// ---------------------------------------------------------------------------
__global__ __launch_bounds__(512, 2) void build_A_mfma_kernel(
    const float* __restrict__ X, const float* __restrict__ q,
    const _Float16* __restrict__ Wf, float* __restrict__ Arow)
{
    __shared__ _Float16 Zh[32 * 40];
    __shared__ _Float16 Zl[32 * 40];
    __shared__ float qs[DD];
    const int t = threadIdx.x;
    const int lane = t & 63;
    const int wv = t >> 6;
    const int wr = wv >> 2;      // 0..1: rows 16*wr..
    const int wc = wv & 3;       // 0..3: cols 128*wc..
    const int q4 = lane >> 4;
    const int l16 = lane & 15;
    const int i0 = blockIdx.x * 32;

    for (int d = t; d < DD; d += 512) qs[d] = q[d];

    floatx4 acc[8];
    #pragma unroll
    for (int ct = 0; ct < 8; ++ct) acc[ct] = (floatx4)0.f;

    const int zr = t >> 4;        // 0..31
    const int zk = (t & 15) * 2;

    for (int term = 0; term < 2; ++term) {
        const _Float16* Wbase = Wf + (size_t)(term ? 2 : 0) * KT * 16384;
        for (int kt = 0; kt < KT; ++kt) {
            __syncthreads();
            {   // stage Z (32 rows x 32 k), hi/lo fp16 split
                const float* xp = X + (size_t)(i0 + zr) * DD + kt * 32 + zk;
                float2 xv = *(const float2*)xp;
                float z0 = xv.x, z1 = xv.y;
                if (term) {
                    z0 = fabsf(z0 - qs[kt * 32 + zk + 0]);
                    z1 = fabsf(z1 - qs[kt * 32 + zk + 1]);
                }
                _Float16 h0 = (_Float16)z0, h1 = (_Float16)z1;
                Zh[zr * 40 + zk + 0] = h0;
                Zh[zr * 40 + zk + 1] = h1;
                Zl[zr * 40 + zk + 0] = (_Float16)(z0 - (float)h0);
                Zl[zr * 40 + zk + 1] = (_Float16)(z1 - (float)h1);
            }
            __syncthreads();
            halfx8 Ah = *(halfx8*)&Zh[(wr * 16 + l16) * 40 + q4 * 8];
            halfx8 Al = *(halfx8*)&Zl[(wr * 16 + l16) * 40 + q4 * 8];
            const _Float16* wp = Wbase + (size_t)kt * 16384
                                 + (size_t)(wc * 8) * 512 + lane * 8;
            #pragma unroll
            for (int ct = 0; ct < 8; ++ct) {
                halfx8 B = *(const halfx8*)(wp + (size_t)ct * 512);
                acc[ct] = __builtin_amdgcn_mfma_f32_16x16x32_f16(Ah, B, acc[ct], 0, 0, 0);
                acc[ct] = __builtin_amdgcn_mfma_f32_16x16x32_f16(Al, B, acc[ct], 0, 0, 0);
            }
        }
    }
    #pragma unroll
    for (int ct = 0; ct < 8; ++ct)
        #pragma unroll
        for (int reg = 0; reg < 4; ++reg) {
            int row = wr * 16 + q4 * 4 + reg;
            int h = wc * 128 + ct * 16 + l16;
            Arow[(size_t)(i0 + row) * HH + h] = acc[ct][reg];
        }
}

// ---------------------------------------------------------------------------
// build_B: Brow[j][h] = b1[h] + y@W1b + |y-q|@W1e. Grid (32 j, 2 h-chunks).
// ---------------------------------------------------------------------------
__global__ __launch_bounds__(256) void build_B_kernel(
    const float* __restrict__ C_init, const float* __restrict__ q,
    const float* __restrict__ W1, const float* __restrict__ b1,
    float* __restrict__ Brow)
{
    __shared__ float ys[DD], ya[DD];
    const int j = blockIdx.x, t = threadIdx.x;
    const int h = blockIdx.y * 256 + t;
    for (int idx = t; idx < DD; idx += 256) {
        float y = C_init[(size_t)j * DD + idx];
        ys[idx] = y;
        ya[idx] = fabsf(y - q[idx]);
    }
    __syncthreads();
    const float* W1b = W1 + (size_t)768 * HH + h;
    const float* W1e = W1 + (size_t)3072 * HH + h;
    float acc = b1[h];
    #pragma unroll 8
    for (int d = 0; d < DD; ++d)
        acc = fmaf(ys[d], W1b[(size_t)d * HH], fmaf(ya[d], W1e[(size_t)d * HH], acc));
    Brow[(size_t)j * HH + h] = acc;
}

// ---------------------------------------------------------------------------
// pairwise_mfma: P = |X - y_j| @ W1c via 2-pass fp16-split MFMA, fused
// epilogue s[i,j] = sum_h relu(P + A + B) * W2[h]. Grid (16, 32).
// ---------------------------------------------------------------------------
__global__ __launch_bounds__(512, 2) void pairwise_mfma_kernel(
    const float* __restrict__ X, const _Float16* __restrict__ Wf,
    const float* __restrict__ Y,
    const float* __restrict__ Arow, const float* __restrict__ Brow,
    const float* __restrict__ W2, float* __restrict__ S)
{
    __shared__ _Float16 Zh[128 * 40];
    __shared__ _Float16 Zl[128 * 40];
    __shared__ float ys[DD];
    __shared__ float Sred[2 * 128];
    const int t = threadIdx.x;
    const int lane = t & 63;
    const int wv = t >> 6;
    const int wr = wv >> 1;
    const int wc = wv & 1;
    const int q4 = lane >> 4;
    const int l16 = lane & 15;
    const int i0 = blockIdx.x * 128;
    const int j  = blockIdx.y;

    for (int d = t; d < DD; d += 512) ys[d] = Y[(size_t)j * DD + d];

    const _Float16* Wc = Wf + (size_t)1 * KT * 16384;

    floatx4 acc[2][16];
    #pragma unroll
    for (int rt = 0; rt < 2; ++rt)
        #pragma unroll
        for (int ct = 0; ct < 16; ++ct) acc[rt][ct] = (floatx4)0.f;

    const int zr = t >> 2;
    const int zk = (t & 3) * 8;

    for (int kt = 0; kt < KT; ++kt) {
        __syncthreads();
        {
            const float* xp = X + (size_t)(i0 + zr) * DD + kt * 32 + zk;
            float4 xa = *(const float4*)xp;
            float4 xb = *(const float4*)(xp + 4);
            float z[8];
            z[0] = fabsf(xa.x - ys[kt * 32 + zk + 0]);
            z[1] = fabsf(xa.y - ys[kt * 32 + zk + 1]);
            z[2] = fabsf(xa.z - ys[kt * 32 + zk + 2]);
            z[3] = fabsf(xa.w - ys[kt * 32 + zk + 3]);
            z[4] = fabsf(xb.x - ys[kt * 32 + zk + 4]);
            z[5] = fabsf(xb.y - ys[kt * 32 + zk + 5]);
            z[6] = fabsf(xb.z - ys[kt * 32 + zk + 6]);
            z[7] = fabsf(xb.w - ys[kt * 32 + zk + 7]);
            halfx8 vh, vl;
            #pragma unroll
            for (int e = 0; e < 8; ++e) {
                _Float16 h = (_Float16)z[e];
                vh[e] = h;
                vl[e] = (_Float16)(z[e] - (float)h);
            }
            *(halfx8*)&Zh[zr * 40 + zk] = vh;
            *(halfx8*)&Zl[zr * 40 + zk] = vl;
        }
        __syncthreads();

        halfx8 Ah[2], Al[2];
        #pragma unroll
        for (int rt = 0; rt < 2; ++rt) {
            int r = wr * 32 + rt * 16 + l16;
            Ah[rt] = *(halfx8*)&Zh[r * 40 + q4 * 8];
            Al[rt] = *(halfx8*)&Zl[r * 40 + q4 * 8];
        }
        const _Float16* wp = Wc + (((size_t)kt * 32 + wc * 16) * 64 + lane) * 8;
        #pragma unroll
        for (int ct = 0; ct < 16; ++ct) {
            halfx8 B = *(const halfx8*)(wp + (size_t)ct * 512);
            #pragma unroll
            for (int rt = 0; rt < 2; ++rt) {
                acc[rt][ct] = __builtin_amdgcn_mfma_f32_16x16x32_f16(Ah[rt], B, acc[rt][ct], 0, 0, 0);
                acc[rt][ct] = __builtin_amdgcn_mfma_f32_16x16x32_f16(Al[rt], B, acc[rt][ct], 0, 0, 0);
            }
        }
    }

    float w2v[16], bv[16];
    #pragma unroll
    for (int ct = 0; ct < 16; ++ct) {
        int h = wc * 256 + ct * 16 + l16;
        w2v[ct] = W2[h];
        bv[ct]  = Brow[(size_t)j * HH + h];
    }
    #pragma unroll
    for (int rt = 0; rt < 2; ++rt) {
        #pragma unroll
        for (int reg = 0; reg < 4; ++reg) {
            int row = wr * 32 + rt * 16 + q4 * 4 + reg;
            const float* ap = Arow + (size_t)(i0 + row) * HH + wc * 256 + l16;
            float s = 0.f;
            #pragma unroll
            for (int ct = 0; ct < 16; ++ct) {
                float pre = acc[rt][ct][reg] + ap[ct * 16] + bv[ct];
                s = fmaf(fmaxf(pre, 0.f), w2v[ct], s);
            }
            s += __shfl_xor(s, 1, 64);
            s += __shfl_xor(s, 2, 64);
            s += __shfl_xor(s, 4, 64);
            s += __shfl_xor(s, 8, 64);
            if (l16 == 0) Sred[wc * 128 + row] = s;
        }
    }
    __syncthreads();
    if (t < 128) S[(size_t)(i0 + t) * MM + j] = Sred[t] + Sred[128 + t];
}

// ---------------------------------------------------------------------------
__global__ __launch_bounds__(256) void softmax_kernel(
    const float* __restrict__ S, const float* __restrict__ b2,
    float* __restrict__ a_out)
{
    const int t = threadIdx.x;
    const int j = t & 31, r = t >> 5;
    const int i = blockIdx.x * 8 + r;
    const float b2v = b2[0];
    float s = S[(size_t)i * MM + j];
    float sig = 1.f / (1.f + expf(-(s + b2v)));
    float l = -sig * (1.0f / TEMP);
    float m = l;
    #pragma unroll
    for (int off = 16; off >= 1; off >>= 1) m = fmaxf(m, __shfl_xor(m, off, 32));
    float e = expf(l - m);
    float sum = e;
    #pragma unroll
    for (int off = 16; off >= 1; off >>= 1) sum += __shfl_xor(sum, off, 32);
    a_out[(size_t)i * MM + j] = e / sum;
}

__global__ __launch_bounds__(256) void cnew_partial_kernel(
    const float* __restrict__ a, const float* __restrict__ X,
    float* __restrict__ Cacc, float* __restrict__ Asum)
{
    const int t = threadIdx.x;
    const int d = blockIdx.x * 256 + t;
    const int j = blockIdx.y;
    const int i0 = blockIdx.z * 256;
    float acc = 0.f, asum = 0.f;
    for (int ii = 0; ii < 256; ++ii) {
        float av = a[(size_t)(i0 + ii) * MM + j];
        asum += av;
        acc = fmaf(av, X[(size_t)(i0 + ii) * DD + d], acc);
    }
    atomicAdd(&Cacc[(size_t)j * DD + d], acc);
    if (blockIdx.x == 0 && t == 0) atomicAdd(&Asum[j], asum);
}

__global__ __launch_bounds__(256) void finalize_kernel(
    const float* __restrict__ Cacc, const float* __restrict__ Asum,
    const float* __restrict__ C_init, float* __restrict__ C_new,
    float* __restrict__ diff)
{
    const int t = threadIdx.x;
    const int d = blockIdx.x * 256 + t;
    const int j = blockIdx.y;
    float c = Cacc[(size_t)j * DD + d] / (Asum[j] + EPS);
    C_new[(size_t)j * DD + d] = c;
    float ad = fabsf(c - C_init[(size_t)j * DD + d]);
    #pragma unroll
    for (int off = 32; off >= 1; off >>= 1) ad += __shfl_xor(ad, off, 64);
    if ((t & 63) == 0) atomicAdd(diff, ad);
}

__global__ __launch_bounds__(256) void select_kernel(
    const float* __restrict__ C_new, const float* __restrict__ C_init,
    const float* __restrict__ diff, float* __restrict__ out)
{
    const int k = blockIdx.x * 256 + threadIdx.x;
    const float dv = *diff;
    out[k] = (dv > THRESH) ? C_new[k] : C_init[k];
}

// ---------------------------------------------------------------------------
extern "C" void kernel_launch(void* const* d_in, const int* in_sizes, int n_in,
                              void* d_out, int out_size, void* d_ws, size_t ws_size,
                              hipStream_t stream)
{
    const float* q      = (const float*)d_in[0];
    const float* X      = (const float*)d_in[1];
    const float* C_init = (const float*)d_in[2];
    const float* W1     = (const float*)d_in[3];
    const float* b1     = (const float*)d_in[4];
    const float* W2     = (const float*)d_in[5];
    const float* b2     = (const float*)d_in[6];

    float* out_C = (float*)d_out;                    // (M, D)
    float* out_a = (float*)d_out + (size_t)MM * DD;  // (N, M)

    float* ws   = (float*)d_ws;
    _Float16* Wf = (_Float16*)ws;                    // 3*24*16384 halves = 589824 floats
    float* Arow = ws + 589824;                       // N*H
    float* Brow = Arow + (size_t)NN * HH;            // M*H
    float* S    = Brow + (size_t)MM * HH;            // N*M
    float* Cacc = S    + (size_t)NN * MM;            // M*D
    float* Asum = Cacc + (size_t)MM * DD;            // M
    float* diff = Asum + MM;                         // 1 (+15 pad)
    float* Cn   = diff + 16;                         // M*D

    hipMemsetAsync(Cacc, 0, ((size_t)MM * DD + MM + 16) * sizeof(float), stream);

    prep_W_kernel<<<3 * KT, 256, 0, stream>>>(W1, Wf);
    build_B_kernel<<<dim3(32, 2), 256, 0, stream>>>(C_init, q, W1, b1, Brow);
    build_A_mfma_kernel<<<64, 512, 0, stream>>>(X, q, Wf, Arow);
    pairwise_mfma_kernel<<<dim3(16, 32), 512, 0, stream>>>(X, Wf, C_init, Arow, Brow, W2, S);
    softmax_kernel<<<256, 256, 0, stream>>>(S, b2, out_a);
    cnew_partial_kernel<<<dim3(3, 32, 8), 256, 0, stream>>>(out_a, X, Cacc, Asum);
    finalize_kernel<<<dim3(3, 32), 256, 0, stream>>>(Cacc, Asum, C_init, Cn, diff);
    select_kernel<<<96, 256, 0, stream>>>(Cn, C_init, diff, out_C);
}